// Round 1
// baseline (397.957 us; speedup 1.0000x reference)
//
#include <hip/hip_runtime.h>
#include <math.h>

#define H 256
#define W 256
#define CH 24
#define NK 63
#define TS 16

// ---------------- RBF helpers (truncated mixture: window +/-6 components) ----
// mean is uniform linspace; components beyond 6 steps contribute < exp(-21) ~ 1e-9.
__device__ __forceinline__ float rbf_val(float v, const float* ms, const float* ws,
                                         int ch, float m0, float inv_step) {
    int kc = (int)floorf((v - m0) * inv_step + 0.5f);
    int lo = kc - 6; if (lo < 0) lo = 0;
    int hi = kc + 6; if (hi > NK - 1) hi = NK - 1;
    float s = 0.f;
    for (int k = lo; k <= hi; ++k) {
        float d = v - ms[k];
        s = fmaf(__expf(d * d * -0.005f), ws[ch * NK + k], s);
    }
    return s;
}
__device__ __forceinline__ float rbf_der(float v, const float* ms, const float* ws,
                                         int ch, float m0, float inv_step) {
    int kc = (int)floorf((v - m0) * inv_step + 0.5f);
    int lo = kc - 6; if (lo < 0) lo = 0;
    int hi = kc + 6; if (hi > NK - 1) hi = NK - 1;
    float s = 0.f;
    for (int k = lo; k <= hi; ++k) {
        float d = v - ms[k];
        s = fmaf(__expf(d * d * -0.005f) * d * -0.01f, ws[ch * NK + k], s);
    }
    return s;
}

// ---------------- filter normalization (Frobenius norm) ----------------------
__global__ void k_norm(const float* __restrict__ f0, const float* __restrict__ f1,
                       float* __restrict__ f0n, float* __restrict__ f1n) {
    __shared__ float red[256];
    int t = threadIdx.x;
    float s = 0.f;
    for (int i = t; i < 600; i += 256) s += f0[i] * f0[i];
    red[t] = s; __syncthreads();
    for (int off = 128; off > 0; off >>= 1) { if (t < off) red[t] += red[t + off]; __syncthreads(); }
    float inv0 = 1.f / sqrtf(red[0]);
    __syncthreads();
    s = 0.f;
    for (int i = t; i < 14400; i += 256) s += f1[i] * f1[i];
    red[t] = s; __syncthreads();
    for (int off = 128; off > 0; off >>= 1) { if (t < off) red[t] += red[t + off]; __syncthreads(); }
    float inv1 = 1.f / sqrtf(red[0]);
    for (int i = t; i < 600; i += 256) f0n[i] = f0[i] * inv0;
    for (int i = t; i < 14400; i += 256) f1n[i] = f1[i] * inv1;
}

// ---------------- conv1 (1->24, replication pad) + rbf(actw0) ----------------
__global__ __launch_bounds__(256) void k_conv1(const float* __restrict__ x,
        const float* __restrict__ f0n, const float* __restrict__ mean,
        const float* __restrict__ actw0, float* __restrict__ tout) {
    __shared__ float xs[20][20];
    __shared__ float fs[600];
    __shared__ float ms[NK];
    __shared__ float ws[CH * NK];
    int tid = threadIdx.x;
    int x0 = blockIdx.x * TS, y0 = blockIdx.y * TS;
    for (int i = tid; i < 400; i += 256) {
        int r = i / 20, cL = i % 20;
        int gy = min(max(y0 + r - 2, 0), H - 1);
        int gx = min(max(x0 + cL - 2, 0), W - 1);
        xs[r][cL] = x[gy * W + gx];
    }
    for (int i = tid; i < 600; i += 256) fs[i] = f0n[i];
    for (int i = tid; i < NK; i += 256) ms[i] = mean[i];
    for (int i = tid; i < CH * NK; i += 256) ws[i] = actw0[i];
    __syncthreads();
    int tx = tid & 15, ty = tid >> 4;
    float in_[25];
    #pragma unroll
    for (int u = 0; u < 5; ++u)
        #pragma unroll
        for (int v = 0; v < 5; ++v) in_[u * 5 + v] = xs[ty + u][tx + v];
    float m0 = ms[0];
    float inv_step = (float)(NK - 1) / (ms[NK - 1] - ms[0]);
    int pix = (y0 + ty) * W + (x0 + tx);
    for (int o = 0; o < CH; ++o) {
        float a = 0.f;
        #pragma unroll
        for (int k = 0; k < 25; ++k) a = fmaf(in_[k], fs[o * 25 + k], a);
        tout[o * (H * W) + pix] = rbf_val(a, ms, ws, o, m0, inv_step);
    }
}

// ---------------- 24->24 conv (MODE 0: conv2+rbf, MODE 1: convT2+rbf') -------
// MODE 0: replication pad, weight f1[o,c,u,v], rbf(actw1)
// MODE 1: zero pad, weight f1[c,o,4-u,4-v] (cropped transpose conv), rbf_deriv(actw0)
template<int MODE>
__global__ __launch_bounds__(256) void k_conv24(const float* __restrict__ tin,
        const float* __restrict__ f1n, const float* __restrict__ mean,
        const float* __restrict__ actw, float* __restrict__ tout) {
    __shared__ float ts[CH][20][20];
    __shared__ float fs[6 * 600];     // 6-input-channel filter chunk
    __shared__ float ms[NK];
    __shared__ float ws[CH * NK];
    int tid = threadIdx.x;
    int x0 = blockIdx.x * TS, y0 = blockIdx.y * TS;
    for (int i = tid; i < CH * 400; i += 256) {
        int c = i / 400, r = (i / 20) % 20, cL = i % 20;
        float v;
        if (MODE == 0) {
            int gy = min(max(y0 + r - 2, 0), H - 1);
            int gx = min(max(x0 + cL - 2, 0), W - 1);
            v = tin[c * (H * W) + gy * W + gx];
        } else {
            int gy = y0 + r - 2, gx = x0 + cL - 2;
            v = (gy >= 0 && gy < H && gx >= 0 && gx < W) ? tin[c * (H * W) + gy * W + gx] : 0.f;
        }
        ts[c][r][cL] = v;
    }
    for (int i = tid; i < NK; i += 256) ms[i] = mean[i];
    for (int i = tid; i < CH * NK; i += 256) ws[i] = actw[i];
    float acc[CH];
    #pragma unroll
    for (int o = 0; o < CH; ++o) acc[o] = 0.f;
    int tx = tid & 15, ty = tid >> 4;
    for (int c0 = 0; c0 < CH; c0 += 6) {
        __syncthreads();
        for (int i = tid; i < 6 * 600; i += 256) {
            int cc = i / 600, rest = i % 600;
            int o = rest / 25, k = rest % 25;
            int c = c0 + cc;
            fs[i] = (MODE == 0) ? f1n[(o * CH + c) * 25 + k]
                                : f1n[(c * CH + o) * 25 + (24 - k)];
        }
        __syncthreads();
        for (int cc = 0; cc < 6; ++cc) {
            int c = c0 + cc;
            float in_[25];
            #pragma unroll
            for (int u = 0; u < 5; ++u)
                #pragma unroll
                for (int v = 0; v < 5; ++v) in_[u * 5 + v] = ts[c][ty + u][tx + v];
            const float* fb = &fs[cc * 600];
            #pragma unroll
            for (int o = 0; o < CH; ++o) {
                float a = acc[o];
                #pragma unroll
                for (int k = 0; k < 25; ++k) a = fmaf(in_[k], fb[o * 25 + k], a);
                acc[o] = a;
            }
        }
    }
    float m0 = ms[0];
    float inv_step = (float)(NK - 1) / (ms[NK - 1] - ms[0]);
    int pix = (y0 + ty) * W + (x0 + tx);
    for (int o = 0; o < CH; ++o) {
        float r = (MODE == 0) ? rbf_val(acc[o], ms, ws, o, m0, inv_step)
                              : rbf_der(acc[o], ms, ws, o, m0, inv_step);
        tout[o * (H * W) + pix] = r;
    }
}

// ---------------- convT1 (24->1, zero pad, flipped) + final combine ----------
__global__ __launch_bounds__(256) void k_final(const float* __restrict__ tin,
        const float* __restrict__ f0n, const float* __restrict__ x,
        const float* __restrict__ y, const float* __restrict__ lamp,
        float* __restrict__ out) {
    __shared__ float ts[CH][20][20];
    __shared__ float fs[600];
    int tid = threadIdx.x;
    int x0 = blockIdx.x * TS, y0 = blockIdx.y * TS;
    for (int i = tid; i < CH * 400; i += 256) {
        int c = i / 400, r = (i / 20) % 20, cL = i % 20;
        int gy = y0 + r - 2, gx = x0 + cL - 2;
        ts[c][r][cL] = (gy >= 0 && gy < H && gx >= 0 && gx < W)
                       ? tin[c * (H * W) + gy * W + gx] : 0.f;
    }
    for (int i = tid; i < 600; i += 256) fs[i] = f0n[(i / 25) * 25 + (24 - i % 25)];
    __syncthreads();
    int tx = tid & 15, ty = tid >> 4;
    float a = 0.f;
    for (int c = 0; c < CH; ++c) {
        #pragma unroll
        for (int u = 0; u < 5; ++u)
            #pragma unroll
            for (int v = 0; v < 5; ++v)
                a = fmaf(ts[c][ty + u][tx + v], fs[c * 25 + u * 5 + v], a);
    }
    int pix = (y0 + ty) * W + (x0 + tx);
    float elam = __expf(lamp[0]);
    float xv = x[pix], yv = y[pix];
    out[pix] = xv - (a + elam * (xv - yv));
}

extern "C" void kernel_launch(void* const* d_in, const int* in_sizes, int n_in,
                              void* d_out, int out_size, void* d_ws, size_t ws_size,
                              hipStream_t stream) {
    const float* x    = (const float*)d_in[0];
    const float* y    = (const float*)d_in[1];
    const float* f0   = (const float*)d_in[3];
    const float* f1   = (const float*)d_in[4];
    const float* aw0  = (const float*)d_in[5];
    const float* aw1  = (const float*)d_in[6];
    const float* mean = (const float*)d_in[7];
    const float* lamp = (const float*)d_in[8];
    float* out = (float*)d_out;

    float* w   = (float*)d_ws;
    float* f0n = w;                 // 600
    float* f1n = w + 640;           // 14400
    float* ta  = w + 16384;         // 24*65536
    float* tb  = ta + CH * H * W;   // 24*65536

    dim3 grid(W / TS, H / TS);
    k_norm<<<1, 256, 0, stream>>>(f0, f1, f0n, f1n);
    k_conv1<<<grid, 256, 0, stream>>>(x, f0n, mean, aw0, ta);
    k_conv24<0><<<grid, 256, 0, stream>>>(ta, f1n, mean, aw1, tb);
    k_conv24<1><<<grid, 256, 0, stream>>>(tb, f1n, mean, aw0, ta);
    k_final<<<grid, 256, 0, stream>>>(ta, f0n, x, y, lamp, out);
}

// Round 2
// 301.656 us; speedup vs baseline: 1.3192x; 1.3192x over previous
//
#include <hip/hip_runtime.h>
#include <math.h>

#define H 256
#define W 256
#define HW (H * W)
#define CH 24
#define NK 63
#define TS 16

// ---------------- RBF helpers (truncated mixture: window +/-6 components) ----
// mean is uniform linspace step 10, sigma^2=100; beyond 6 steps < 1.5e-8.
__device__ __forceinline__ float rbf_val(float v, const float* ms, const float* ws,
                                         int ch, float m0, float inv_step) {
    int kc = (int)floorf((v - m0) * inv_step + 0.5f);
    int lo = kc - 6; if (lo < 0) lo = 0;
    int hi = kc + 6; if (hi > NK - 1) hi = NK - 1;
    float s = 0.f;
    for (int k = lo; k <= hi; ++k) {
        float d = v - ms[k];
        s = fmaf(__expf(d * d * -0.005f), ws[ch * NK + k], s);
    }
    return s;
}
__device__ __forceinline__ float rbf_der(float v, const float* ms, const float* ws,
                                         int ch, float m0, float inv_step) {
    int kc = (int)floorf((v - m0) * inv_step + 0.5f);
    int lo = kc - 6; if (lo < 0) lo = 0;
    int hi = kc + 6; if (hi > NK - 1) hi = NK - 1;
    float s = 0.f;
    for (int k = lo; k <= hi; ++k) {
        float d = v - ms[k];
        s = fmaf(__expf(d * d * -0.005f) * d * -0.01f, ws[ch * NK + k], s);
    }
    return s;
}

// ---------------- filter normalization + pre-transposed layouts --------------
// outputs: f0n[o*25+k]            (conv1 weights, normalized)
//          f0t[c*25+k]  = f0n[c*25+(24-k)]            (convT1, flipped)
//          fA [(o*24+c)*25+k] = f1n same layout       (conv2)
//          fB [(o*24+c)*25+k] = f1n[(c*24+o)*25+(24-k)] (convT2, swapped+flipped)
__global__ void k_norm(const float* __restrict__ f0, const float* __restrict__ f1,
                       float* __restrict__ f0n, float* __restrict__ f0t,
                       float* __restrict__ fA, float* __restrict__ fB) {
    __shared__ float red[256];
    int t = threadIdx.x;
    float s = 0.f;
    for (int i = t; i < 600; i += 256) s += f0[i] * f0[i];
    red[t] = s; __syncthreads();
    for (int off = 128; off > 0; off >>= 1) { if (t < off) red[t] += red[t + off]; __syncthreads(); }
    float inv0 = 1.f / sqrtf(red[0]);
    __syncthreads();
    s = 0.f;
    for (int i = t; i < 14400; i += 256) s += f1[i] * f1[i];
    red[t] = s; __syncthreads();
    for (int off = 128; off > 0; off >>= 1) { if (t < off) red[t] += red[t + off]; __syncthreads(); }
    float inv1 = 1.f / sqrtf(red[0]);
    for (int i = t; i < 600; i += 256) {
        int c = i / 25, k = i % 25;
        f0n[i] = f0[i] * inv0;
        f0t[i] = f0[c * 25 + (24 - k)] * inv0;
    }
    for (int i = t; i < 14400; i += 256) {
        int oc = i / 25, k = i % 25;
        int o = oc / CH, c = oc % CH;
        fA[i] = f1[i] * inv1;
        fB[i] = f1[(c * CH + o) * 25 + (24 - k)] * inv1;
    }
}

// ---------------- conv1 (1->24, replication pad) + rbf(actw0) ----------------
// filter read from global with uniform indices -> scalar loads (SGPR operand)
__global__ __launch_bounds__(256) void k_conv1(const float* __restrict__ x,
        const float* __restrict__ f0n, const float* __restrict__ mean,
        const float* __restrict__ actw0, float* __restrict__ tout) {
    __shared__ float xs[20][20];
    __shared__ float ms[NK];
    __shared__ float ws[CH * NK];
    int tid = threadIdx.x;
    int x0 = blockIdx.x * TS, y0 = blockIdx.y * TS;
    for (int i = tid; i < 400; i += 256) {
        int r = i / 20, cL = i % 20;
        int gy = min(max(y0 + r - 2, 0), H - 1);
        int gx = min(max(x0 + cL - 2, 0), W - 1);
        xs[r][cL] = x[gy * W + gx];
    }
    for (int i = tid; i < NK; i += 256) ms[i] = mean[i];
    for (int i = tid; i < CH * NK; i += 256) ws[i] = actw0[i];
    __syncthreads();
    int tx = tid & 15, ty = tid >> 4;
    float in_[25];
    #pragma unroll
    for (int u = 0; u < 5; ++u)
        #pragma unroll
        for (int v = 0; v < 5; ++v) in_[u * 5 + v] = xs[ty + u][tx + v];
    float m0 = ms[0];
    float inv_step = (float)(NK - 1) / (ms[NK - 1] - ms[0]);
    int pix = (y0 + ty) * W + (x0 + tx);
    #pragma unroll
    for (int o = 0; o < CH; ++o) {
        float a = 0.f;
        #pragma unroll
        for (int k = 0; k < 25; ++k) a = fmaf(in_[k], f0n[o * 25 + k], a);
        tout[o * HW + pix] = rbf_val(a, ms, ws, o, m0, inv_step);
    }
}

// ---------------- 24->24 conv, 512 threads, 2-way input-channel split --------
// MODE 0: replication pad + rbf_val(actw);  MODE 1: zero pad + rbf_der(actw)
// filter f[(o*24+c)*25+k] read from global with wave-uniform indices.
template<int MODE>
__global__ __launch_bounds__(512) void k_conv24(const float* __restrict__ tin,
        const float* __restrict__ f, const float* __restrict__ mean,
        const float* __restrict__ actw, float* __restrict__ tout) {
    __shared__ float sm[9600];            // in tile [24][20][20]; reused as exchange buf
    __shared__ float ms[NK];
    __shared__ float ws[CH * NK];
    int tid = threadIdx.x;
    int x0 = blockIdx.x * TS, y0 = blockIdx.y * TS;
    for (int i = tid; i < CH * 400; i += 512) {
        int c = i / 400, r = (i / 20) % 20, cL = i % 20;
        float v;
        if (MODE == 0) {
            int gy = min(max(y0 + r - 2, 0), H - 1);
            int gx = min(max(x0 + cL - 2, 0), W - 1);
            v = tin[c * HW + gy * W + gx];
        } else {
            int gy = y0 + r - 2, gx = x0 + cL - 2;
            v = (gy >= 0 && gy < H && gx >= 0 && gx < W) ? tin[c * HW + gy * W + gx] : 0.f;
        }
        sm[i] = v;
    }
    for (int i = tid; i < NK; i += 512) ms[i] = mean[i];
    for (int i = tid; i < CH * NK; i += 512) ws[i] = actw[i];
    __syncthreads();

    int p = tid & 255;                    // pixel within 16x16 tile
    int ch = tid >> 8;                    // which half of input channels
    int chU = __builtin_amdgcn_readfirstlane(ch);   // force wave-uniform
    int tx = p & 15, ty = p >> 4;

    float acc[CH];
    #pragma unroll
    for (int o = 0; o < CH; ++o) acc[o] = 0.f;

    for (int cc = 0; cc < 12; ++cc) {
        int c = chU * 12 + cc;            // wave-uniform channel index
        float in_[25];
        #pragma unroll
        for (int u = 0; u < 5; ++u)
            #pragma unroll
            for (int v = 0; v < 5; ++v)
                in_[u * 5 + v] = sm[c * 400 + (ty + u) * 20 + (tx + v)];
        #pragma unroll
        for (int o = 0; o < CH; ++o) {
            float a = acc[o];
            #pragma unroll
            for (int k = 0; k < 25; ++k)
                a = fmaf(in_[k], f[(o * CH + c) * 25 + k], a);
            acc[o] = a;
        }
    }
    __syncthreads();   // done reading input tile; reuse sm as exchange buffer

    // exchange: lower half owns out-channels 0..11, upper half owns 12..23.
    // each half writes the 12 partial sums the other half owns (stride 13: no conflicts)
    float* red0 = sm;                     // partials of ch 0..11 (written by upper)
    float* red1 = sm + 3328;              // partials of ch 12..23 (written by lower)
    if (ch == 0) {
        #pragma unroll
        for (int j = 0; j < 12; ++j) red1[p * 13 + j] = acc[12 + j];
    } else {
        #pragma unroll
        for (int j = 0; j < 12; ++j) red0[p * 13 + j] = acc[j];
    }
    __syncthreads();

    float m0 = ms[0];
    float inv_step = (float)(NK - 1) / (ms[NK - 1] - ms[0]);
    int pix = (y0 + ty) * W + (x0 + tx);
    if (ch == 0) {
        #pragma unroll
        for (int j = 0; j < 12; ++j) {
            float a = acc[j] + red0[p * 13 + j];
            float r = (MODE == 0) ? rbf_val(a, ms, ws, j, m0, inv_step)
                                  : rbf_der(a, ms, ws, j, m0, inv_step);
            tout[j * HW + pix] = r;
        }
    } else {
        #pragma unroll
        for (int j = 0; j < 12; ++j) {
            int o = 12 + j;
            float a = acc[o] + red1[p * 13 + j];
            float r = (MODE == 0) ? rbf_val(a, ms, ws, o, m0, inv_step)
                                  : rbf_der(a, ms, ws, o, m0, inv_step);
            tout[o * HW + pix] = r;
        }
    }
}

// ---------------- convT1 (24->1, zero pad, pre-flipped f0t) + final ----------
__global__ __launch_bounds__(256) void k_final(const float* __restrict__ tin,
        const float* __restrict__ f0t, const float* __restrict__ x,
        const float* __restrict__ y, const float* __restrict__ lamp,
        float* __restrict__ out) {
    __shared__ float ts[CH][20][20];
    int tid = threadIdx.x;
    int x0 = blockIdx.x * TS, y0 = blockIdx.y * TS;
    for (int i = tid; i < CH * 400; i += 256) {
        int c = i / 400, r = (i / 20) % 20, cL = i % 20;
        int gy = y0 + r - 2, gx = x0 + cL - 2;
        ts[c][r][cL] = (gy >= 0 && gy < H && gx >= 0 && gx < W)
                       ? tin[c * HW + gy * W + gx] : 0.f;
    }
    __syncthreads();
    int tx = tid & 15, ty = tid >> 4;
    float a = 0.f;
    for (int c = 0; c < CH; ++c) {
        #pragma unroll
        for (int u = 0; u < 5; ++u)
            #pragma unroll
            for (int v = 0; v < 5; ++v)
                a = fmaf(ts[c][ty + u][tx + v], f0t[c * 25 + u * 5 + v], a);
    }
    int pix = (y0 + ty) * W + (x0 + tx);
    float elam = __expf(lamp[0]);
    float xv = x[pix], yv = y[pix];
    out[pix] = xv - (a + elam * (xv - yv));
}

extern "C" void kernel_launch(void* const* d_in, const int* in_sizes, int n_in,
                              void* d_out, int out_size, void* d_ws, size_t ws_size,
                              hipStream_t stream) {
    const float* x    = (const float*)d_in[0];
    const float* y    = (const float*)d_in[1];
    const float* f0   = (const float*)d_in[3];
    const float* f1   = (const float*)d_in[4];
    const float* aw0  = (const float*)d_in[5];
    const float* aw1  = (const float*)d_in[6];
    const float* mean = (const float*)d_in[7];
    const float* lamp = (const float*)d_in[8];
    float* out = (float*)d_out;

    float* w   = (float*)d_ws;
    float* f0n = w;                  // 600
    float* f0t = w + 640;            // 600
    float* fA  = w + 1280;           // 14400
    float* fB  = w + 16384;          // 14400
    float* ta  = w + 32768;          // 24*65536
    float* tb  = ta + CH * HW;       // 24*65536

    dim3 grid(W / TS, H / TS);
    k_norm<<<1, 256, 0, stream>>>(f0, f1, f0n, f0t, fA, fB);
    k_conv1<<<grid, 256, 0, stream>>>(x, f0n, mean, aw0, ta);
    k_conv24<0><<<grid, 512, 0, stream>>>(ta, fA, mean, aw1, tb);
    k_conv24<1><<<grid, 512, 0, stream>>>(tb, fB, mean, aw0, ta);
    k_final<<<grid, 256, 0, stream>>>(ta, f0t, x, y, lamp, out);
}

// Round 3
// 161.735 us; speedup vs baseline: 2.4606x; 1.8651x over previous
//
#include <hip/hip_runtime.h>
#include <math.h>

#define H 256
#define W 256
#define HW (H * W)
#define CH 24
#define NK 63
#define BT 8            // 8x8 pixel tile
#define TD 12           // tile + 2*2 halo

// ---------------- RBF helpers: fixed 13-tap window (no divergence) -----------
// means are uniform linspace step ~10, sigma^2 = 100; terms beyond 6 steps
// are < exp(-18) ~ 1.5e-8. Clamping the CENTER to [6, NK-7] keeps a superset
// of all significant components for edge values.
__device__ __forceinline__ float rbf_val(float v, const float* ms, const float* ws,
                                         int ch, float m0, float inv_step) {
    int kc = (int)floorf((v - m0) * inv_step + 0.5f);
    kc = min(max(kc, 6), NK - 7);
    float s = 0.f;
    #pragma unroll
    for (int j = 0; j < 13; ++j) {
        int k = kc - 6 + j;
        float d = v - ms[k];
        s = fmaf(__expf(d * d * -0.005f), ws[ch * NK + k], s);
    }
    return s;
}
__device__ __forceinline__ float rbf_der(float v, const float* ms, const float* ws,
                                         int ch, float m0, float inv_step) {
    int kc = (int)floorf((v - m0) * inv_step + 0.5f);
    kc = min(max(kc, 6), NK - 7);
    float s = 0.f;
    #pragma unroll
    for (int j = 0; j < 13; ++j) {
        int k = kc - 6 + j;
        float d = v - ms[k];
        s = fmaf(__expf(d * d * -0.005f) * d * -0.01f, ws[ch * NK + k], s);
    }
    return s;
}

// ---------------- filter normalization + pre-transposed c-major layouts ------
// f0n[o*25+k]                  conv1
// f0t[c*25+k] = f0n[c][24-k]   convT1 (flipped)
// fA[(c*24+o)*25+k] = f1n[(o*24+c)*25+k]        conv2   (c-major)
// fB[(c*24+o)*25+k] = f1n[(c*24+o)*25+(24-k)]   convT2  (c-major, swap+flip)
__global__ void k_norm(const float* __restrict__ f0, const float* __restrict__ f1,
                       float* __restrict__ f0n, float* __restrict__ f0t,
                       float* __restrict__ fA, float* __restrict__ fB) {
    __shared__ float red[256];
    int t = threadIdx.x;
    float s = 0.f;
    for (int i = t; i < 600; i += 256) s += f0[i] * f0[i];
    red[t] = s; __syncthreads();
    for (int off = 128; off > 0; off >>= 1) { if (t < off) red[t] += red[t + off]; __syncthreads(); }
    float inv0 = 1.f / sqrtf(red[0]);
    __syncthreads();
    s = 0.f;
    for (int i = t; i < 14400; i += 256) s += f1[i] * f1[i];
    red[t] = s; __syncthreads();
    for (int off = 128; off > 0; off >>= 1) { if (t < off) red[t] += red[t + off]; __syncthreads(); }
    float inv1 = 1.f / sqrtf(red[0]);
    for (int i = t; i < 600; i += 256) {
        int c = i / 25, k = i % 25;
        f0n[i] = f0[i] * inv0;
        f0t[i] = f0[c * 25 + (24 - k)] * inv0;
    }
    for (int i = t; i < 14400; i += 256) {
        int co = i / 25, k = i % 25;
        int c = co / CH, o = co % CH;
        fA[i] = f1[(o * CH + c) * 25 + k] * inv1;
        fB[i] = f1[(c * CH + o) * 25 + (24 - k)] * inv1;
    }
}

// ---------------- conv1 (1->24, replication pad) + rbf(actw0) ----------------
// 256 thr = 4 groups x 64 px; group g computes out-channels [6g, 6g+6)
__global__ __launch_bounds__(256) void k_conv1(const float* __restrict__ x,
        const float* __restrict__ f0n, const float* __restrict__ mean,
        const float* __restrict__ actw0, float* __restrict__ tout) {
    __shared__ float xs[TD * TD];
    __shared__ float ms[NK];
    __shared__ float ws[CH * NK];
    int tid = threadIdx.x;
    int x0 = blockIdx.x * BT, y0 = blockIdx.y * BT;
    for (int i = tid; i < TD * TD; i += 256) {
        int r = i / TD, cL = i % TD;
        int gy = min(max(y0 + r - 2, 0), H - 1);
        int gx = min(max(x0 + cL - 2, 0), W - 1);
        xs[i] = x[gy * W + gx];
    }
    for (int i = tid; i < NK; i += 256) ms[i] = mean[i];
    for (int i = tid; i < CH * NK; i += 256) ws[i] = actw0[i];
    __syncthreads();
    int g = __builtin_amdgcn_readfirstlane(tid >> 6);
    int px = tid & 63, tx = px & 7, ty = px >> 3;
    float in_[25];
    #pragma unroll
    for (int u = 0; u < 5; ++u)
        #pragma unroll
        for (int v = 0; v < 5; ++v) in_[u * 5 + v] = xs[(ty + u) * TD + tx + v];
    float m0 = ms[0];
    float inv_step = (float)(NK - 1) / (ms[NK - 1] - ms[0]);
    int pix = (y0 + ty) * W + (x0 + tx);
    #pragma unroll 1
    for (int j = 0; j < 6; ++j) {
        int o = g * 6 + j;
        const float* fb = f0n + o * 25;
        float a = 0.f;
        #pragma unroll
        for (int k = 0; k < 25; ++k) a = fmaf(in_[k], fb[k], a);
        tout[o * HW + pix] = rbf_val(a, ms, ws, o, m0, inv_step);
    }
}

// ---------------- 24->24 conv, 4-way input-channel split ---------------------
// MODE 0: replication pad + rbf_val;  MODE 1: zero pad + rbf_der
// group g accumulates input channels [6g,6g+6) into acc[24] (static indexing),
// then all partials are exchanged via LDS (pixel-minor, conflict-free).
template<int MODE>
__global__ __launch_bounds__(256) void k_conv24(const float* __restrict__ tin,
        const float* __restrict__ f, const float* __restrict__ mean,
        const float* __restrict__ actw, float* __restrict__ tout) {
    __shared__ float sm[4 * CH * 64];   // union: tile 24*144=3456 / xchg 6144
    __shared__ float ms[NK];
    __shared__ float ws[CH * NK];
    int tid = threadIdx.x;
    int x0 = blockIdx.x * BT, y0 = blockIdx.y * BT;
    for (int i = tid; i < CH * TD * TD; i += 256) {
        int c = i / (TD * TD), r = (i / TD) % TD, cL = i % TD;
        float v;
        if (MODE == 0) {
            int gy = min(max(y0 + r - 2, 0), H - 1);
            int gx = min(max(x0 + cL - 2, 0), W - 1);
            v = tin[c * HW + gy * W + gx];
        } else {
            int gy = y0 + r - 2, gx = x0 + cL - 2;
            v = (gy >= 0 && gy < H && gx >= 0 && gx < W) ? tin[c * HW + gy * W + gx] : 0.f;
        }
        sm[i] = v;
    }
    for (int i = tid; i < NK; i += 256) ms[i] = mean[i];
    for (int i = tid; i < CH * NK; i += 256) ws[i] = actw[i];
    __syncthreads();

    int g = __builtin_amdgcn_readfirstlane(tid >> 6);
    int px = tid & 63, tx = px & 7, ty = px >> 3;

    float acc[CH];
    #pragma unroll
    for (int o = 0; o < CH; ++o) acc[o] = 0.f;

    #pragma unroll 1
    for (int cc = 0; cc < 6; ++cc) {
        int c = g * 6 + cc;                     // wave-uniform
        float in_[25];
        #pragma unroll
        for (int u = 0; u < 5; ++u)
            #pragma unroll
            for (int v = 0; v < 5; ++v)
                in_[u * 5 + v] = sm[c * (TD * TD) + (ty + u) * TD + tx + v];
        const float* fb = f + c * 600;          // 600 contiguous floats (c-major)
        #pragma unroll
        for (int o = 0; o < CH; ++o) {
            float a = acc[o];
            #pragma unroll
            for (int k = 0; k < 25; ++k) a = fmaf(in_[k], fb[o * 25 + k], a);
            acc[o] = a;
        }
    }
    __syncthreads();   // tile no longer needed; reuse sm as exchange buffer

    #pragma unroll
    for (int j = 0; j < CH; ++j) sm[(g * CH + j) * 64 + px] = acc[j];
    __syncthreads();

    float m0 = ms[0];
    float inv_step = (float)(NK - 1) / (ms[NK - 1] - ms[0]);
    int pix = (y0 + ty) * W + (x0 + tx);
    #pragma unroll 1
    for (int j = 0; j < 6; ++j) {
        int o = g * 6 + j;
        float a = sm[o * 64 + px] + sm[(CH + o) * 64 + px]
                + sm[(2 * CH + o) * 64 + px] + sm[(3 * CH + o) * 64 + px];
        float r = (MODE == 0) ? rbf_val(a, ms, ws, o, m0, inv_step)
                              : rbf_der(a, ms, ws, o, m0, inv_step);
        tout[o * HW + pix] = r;
    }
}

// ---------------- convT1 (24->1, zero pad, pre-flipped) + final combine ------
__global__ __launch_bounds__(256) void k_final(const float* __restrict__ tin,
        const float* __restrict__ f0t, const float* __restrict__ x,
        const float* __restrict__ y, const float* __restrict__ lamp,
        float* __restrict__ out) {
    __shared__ float ts[CH * TD * TD];
    __shared__ float red[4 * 64];
    int tid = threadIdx.x;
    int x0 = blockIdx.x * BT, y0 = blockIdx.y * BT;
    for (int i = tid; i < CH * TD * TD; i += 256) {
        int c = i / (TD * TD), r = (i / TD) % TD, cL = i % TD;
        int gy = y0 + r - 2, gx = x0 + cL - 2;
        ts[i] = (gy >= 0 && gy < H && gx >= 0 && gx < W)
                ? tin[c * HW + gy * W + gx] : 0.f;
    }
    __syncthreads();
    int g = __builtin_amdgcn_readfirstlane(tid >> 6);
    int px = tid & 63, tx = px & 7, ty = px >> 3;
    float a = 0.f;
    #pragma unroll 1
    for (int cc = 0; cc < 6; ++cc) {
        int c = g * 6 + cc;
        const float* fb = f0t + c * 25;
        #pragma unroll
        for (int u = 0; u < 5; ++u)
            #pragma unroll
            for (int v = 0; v < 5; ++v)
                a = fmaf(ts[c * (TD * TD) + (ty + u) * TD + tx + v], fb[u * 5 + v], a);
    }
    red[g * 64 + px] = a;
    __syncthreads();
    if (g == 0) {
        float t = red[px] + red[64 + px] + red[128 + px] + red[192 + px];
        int pix = (y0 + ty) * W + (x0 + tx);
        float elam = __expf(lamp[0]);
        float xv = x[pix], yv = y[pix];
        out[pix] = xv - (t + elam * (xv - yv));
    }
}

extern "C" void kernel_launch(void* const* d_in, const int* in_sizes, int n_in,
                              void* d_out, int out_size, void* d_ws, size_t ws_size,
                              hipStream_t stream) {
    const float* x    = (const float*)d_in[0];
    const float* y    = (const float*)d_in[1];
    const float* f0   = (const float*)d_in[3];
    const float* f1   = (const float*)d_in[4];
    const float* aw0  = (const float*)d_in[5];
    const float* aw1  = (const float*)d_in[6];
    const float* mean = (const float*)d_in[7];
    const float* lamp = (const float*)d_in[8];
    float* out = (float*)d_out;

    float* w   = (float*)d_ws;
    float* f0n = w;                  // 600
    float* f0t = w + 640;            // 600
    float* fA  = w + 1280;           // 14400
    float* fB  = w + 16384;          // 14400
    float* ta  = w + 32768;          // 24*65536
    float* tb  = ta + CH * HW;       // 24*65536

    dim3 grid(W / BT, H / BT);       // 32 x 32 = 1024 blocks
    k_norm<<<1, 256, 0, stream>>>(f0, f1, f0n, f0t, fA, fB);
    k_conv1<<<grid, 256, 0, stream>>>(x, f0n, mean, aw0, ta);
    k_conv24<0><<<grid, 256, 0, stream>>>(ta, fA, mean, aw1, tb);
    k_conv24<1><<<grid, 256, 0, stream>>>(tb, fB, mean, aw0, ta);
    k_final<<<grid, 256, 0, stream>>>(ta, f0t, x, y, lamp, out);
}

// Round 4
// 83.544 us; speedup vs baseline: 4.7635x; 1.9359x over previous
//
#include <hip/hip_runtime.h>
#include <math.h>

#define H 256
#define W 256
#define HW (H * W)
#define CH 24
#define NK 63

typedef short v8s __attribute__((ext_vector_type(8)));
typedef float v4f __attribute__((ext_vector_type(4)));

// ---------------- RBF helpers: 9-tap window (J=+/-4) -------------------------
// means: uniform linspace step 10, sigma^2=100; truncation err ~2*exp(-8)*|w|
__device__ __forceinline__ float rbf_val(float v, const float* ms, const float* ws,
                                         int ch, float m0, float inv_step) {
    int kc = (int)floorf((v - m0) * inv_step + 0.5f);
    kc = min(max(kc, 4), NK - 5);
    float s = 0.f;
    #pragma unroll
    for (int j = 0; j < 9; ++j) {
        int k = kc - 4 + j;
        float d = v - ms[k];
        s = fmaf(__expf(d * d * -0.005f), ws[ch * NK + k], s);
    }
    return s;
}
__device__ __forceinline__ float rbf_der(float v, const float* ms, const float* ws,
                                         int ch, float m0, float inv_step) {
    int kc = (int)floorf((v - m0) * inv_step + 0.5f);
    kc = min(max(kc, 4), NK - 5);
    float s = 0.f;
    #pragma unroll
    for (int j = 0; j < 9; ++j) {
        int k = kc - 4 + j;
        float d = v - ms[k];
        s = fmaf(__expf(d * d * -0.005f) * d * -0.01f, ws[ch * NK + k], s);
    }
    return s;
}

__device__ __forceinline__ short f2bf(float v) {
    unsigned u = __float_as_uint(v);
    u += 0x7fff + ((u >> 16) & 1);
    return (short)(u >> 16);
}

// ---------------- prep: norms, f0n/f0t, and MFMA A-fragment pack -------------
// Abuf layout: [mode 2][mtile 2][kstep 19][lane 64] of v8s (8 bf16 per lane).
// k-order: k = t*24 + c (tap-major, channel-minor), K padded 600->608.
// A row o = mtile*16 + (lane&15); k = 32*s + 8*(lane>>4) + j.
// mode0 (conv2):  W[o][t,c] = f1n[(o*24+c)*25 + t]
// mode1 (convT2): W[o][t,c] = f1n[(c*24+o)*25 + (24-t)]
__global__ void k_prep(const float* __restrict__ f0, const float* __restrict__ f1,
                       float* __restrict__ f0n, float* __restrict__ f0t,
                       v8s* __restrict__ abuf) {
    __shared__ float red[256];
    int tid = threadIdx.x;
    float s1 = 0.f;
    for (int i = tid; i < 14400; i += 256) s1 += f1[i] * f1[i];
    red[tid] = s1; __syncthreads();
    for (int off = 128; off; off >>= 1) { if (tid < off) red[tid] += red[tid + off]; __syncthreads(); }
    float inv1 = 1.f / sqrtf(red[0]);
    __syncthreads();
    if (blockIdx.x == 0) {
        float s0 = 0.f;
        for (int i = tid; i < 600; i += 256) s0 += f0[i] * f0[i];
        red[tid] = s0; __syncthreads();
        for (int off = 128; off; off >>= 1) { if (tid < off) red[tid] += red[tid + off]; __syncthreads(); }
        float inv0 = 1.f / sqrtf(red[0]);
        for (int i = tid; i < 600; i += 256) {
            int c = i / 25, k = i % 25;
            f0n[i] = f0[i] * inv0;
            f0t[i] = f0[c * 25 + (24 - k)] * inv0;
        }
    }
    // A-fragment pack: 4864 jobs = 19 blocks x 256 threads
    int gid = blockIdx.x * 256 + tid;
    int lane = gid & 63;
    int rest = gid >> 6;          // 0..75
    int s = rest % 19;
    int md = rest / 19;           // 0..3
    int mode = md >> 1, m = md & 1;
    int o = m * 16 + (lane & 15);
    v8s av;
    #pragma unroll
    for (int j = 0; j < 8; ++j) {
        int k = 32 * s + 8 * (lane >> 4) + j;
        float wv = 0.f;
        if (o < CH && k < 600) {
            int t = k / 24, c = k % 24;
            wv = (mode == 0) ? f1[(o * CH + c) * 25 + t]
                             : f1[(c * CH + o) * 25 + (24 - t)];
            wv *= inv1;
        }
        av[j] = f2bf(wv);
    }
    abuf[gid] = av;
}

// ---------------- conv1 (1->24, replication pad) + rbf(actw0) ----------------
__global__ __launch_bounds__(256) void k_conv1(const float* __restrict__ x,
        const float* __restrict__ f0n, const float* __restrict__ mean,
        const float* __restrict__ actw0, float* __restrict__ tout) {
    __shared__ float xs[12 * 12];
    __shared__ float ms[NK];
    __shared__ float ws[CH * NK];
    int tid = threadIdx.x;
    int x0 = blockIdx.x * 8, y0 = blockIdx.y * 8;
    for (int i = tid; i < 144; i += 256) {
        int r = i / 12, cL = i % 12;
        int gy = min(max(y0 + r - 2, 0), H - 1);
        int gx = min(max(x0 + cL - 2, 0), W - 1);
        xs[i] = x[gy * W + gx];
    }
    for (int i = tid; i < NK; i += 256) ms[i] = mean[i];
    for (int i = tid; i < CH * NK; i += 256) ws[i] = actw0[i];
    __syncthreads();
    int g = __builtin_amdgcn_readfirstlane(tid >> 6);
    int px = tid & 63, tx = px & 7, ty = px >> 3;
    float in_[25];
    #pragma unroll
    for (int u = 0; u < 5; ++u)
        #pragma unroll
        for (int v = 0; v < 5; ++v) in_[u * 5 + v] = xs[(ty + u) * 12 + tx + v];
    float m0 = ms[0];
    float inv_step = (float)(NK - 1) / (ms[NK - 1] - ms[0]);
    int pix = (y0 + ty) * W + (x0 + tx);
    #pragma unroll 1
    for (int j = 0; j < 6; ++j) {
        int o = g * 6 + j;
        const float* fb = f0n + o * 25;
        float a = 0.f;
        #pragma unroll
        for (int k = 0; k < 25; ++k) a = fmaf(in_[k], fb[k], a);
        tout[o * HW + pix] = rbf_val(a, ms, ws, o, m0, inv_step);
    }
}

// ---------------- 24->24 conv via MFMA implicit GEMM -------------------------
// block: 16x4 pixel tile, 4 waves (wave = one pixel row), 256 thr, grid 16x64.
// LDS tile [yi 0..8][xi 0..19][c 0..23] bf16, channel-minor (x-stride 48B).
// MODE 0: replication pad + rbf_val(actw); MODE 1: zero pad + rbf_der(actw).
template<int MODE>
__global__ __launch_bounds__(256) void k_conv24m(const float* __restrict__ tin,
        const v8s* __restrict__ abuf, const float* __restrict__ mean,
        const float* __restrict__ actw, float* __restrict__ tout) {
    __shared__ __align__(16) short tile[9 * 20 * 24];
    __shared__ float ms[NK];
    __shared__ float ws[CH * NK];
    int tid = threadIdx.x;
    int x0 = blockIdx.x * 16, y0 = blockIdx.y * 4;
    for (int i = tid; i < NK; i += 256) ms[i] = mean[i];
    for (int i = tid; i < CH * NK; i += 256) ws[i] = actw[i];
    // stage: i enumerates ((yi*24 + c)*20 + xi) for global-x coalescing
    for (int i = tid; i < 9 * 20 * 24; i += 256) {
        int q20 = (i * 3277) >> 16;          // i / 20   (exact for i < 16379)
        int xi = i - q20 * 20;
        int yi = (q20 * 2731) >> 16;         // q20 / 24 (exact for q20 < 8183)
        int c  = q20 - yi * 24;
        float v = 0.f;
        if (yi < 8) {
            int gy = y0 + yi - 2, gx = x0 + xi - 2;
            if (MODE == 0) {
                gy = min(max(gy, 0), H - 1); gx = min(max(gx, 0), W - 1);
                v = tin[c * HW + gy * W + gx];
            } else {
                v = (gy >= 0 && gy < H && gx >= 0 && gx < W)
                    ? tin[c * HW + gy * W + gx] : 0.f;
            }
        }
        tile[(yi * 20 + xi) * 24 + c] = f2bf(v);
    }
    __syncthreads();

    int lane = tid & 63;
    int ry   = tid >> 6;                 // wave id = pixel row in tile
    int p    = lane & 15;                // pixel x (and C-frag col)
    int q    = lane >> 4;

    const v8s* ap = abuf + MODE * 2432;  // [m][s][lane]
    v4f acc0 = {0.f, 0.f, 0.f, 0.f};
    v4f acc1 = {0.f, 0.f, 0.f, 0.f};
    #pragma unroll
    for (int s = 0; s < 19; ++s) {
        int k0 = 32 * s + 8 * q;
        int t  = (k0 * 2731) >> 16;      // k0 / 24
        int c0 = k0 - t * 24;
        int u  = (t * 3277) >> 14;       // t / 5
        int v  = t - 5 * u;
        int idx = ((ry + u) * 20 + (p + v)) * 24 + c0;   // 16B-aligned
        v8s b  = *(const v8s*)&tile[idx];
        v8s a0 = ap[s * 64 + lane];
        v8s a1 = ap[1216 + s * 64 + lane];
        acc0 = __builtin_amdgcn_mfma_f32_16x16x32_bf16(a0, b, acc0, 0, 0, 0);
        acc1 = __builtin_amdgcn_mfma_f32_16x16x32_bf16(a1, b, acc1, 0, 0, 0);
    }

    // epilogue: lane holds pixel (x0+p, y0+ry), channels q*4+j and 16+q*4+j
    float m0 = ms[0];
    float inv_step = (float)(NK - 1) / (ms[NK - 1] - m0);
    int pix = (y0 + ry) * W + (x0 + p);
    #pragma unroll
    for (int j = 0; j < 4; ++j) {
        int o = q * 4 + j;
        float a = acc0[j];
        float r = (MODE == 0) ? rbf_val(a, ms, ws, o, m0, inv_step)
                              : rbf_der(a, ms, ws, o, m0, inv_step);
        tout[o * HW + pix] = r;
    }
    if (q < 2) {
        #pragma unroll
        for (int j = 0; j < 4; ++j) {
            int o = 16 + q * 4 + j;
            float a = acc1[j];
            float r = (MODE == 0) ? rbf_val(a, ms, ws, o, m0, inv_step)
                                  : rbf_der(a, ms, ws, o, m0, inv_step);
            tout[o * HW + pix] = r;
        }
    }
}

// ---------------- convT1 (24->1, zero pad, pre-flipped) + final combine ------
__global__ __launch_bounds__(256) void k_final(const float* __restrict__ tin,
        const float* __restrict__ f0t, const float* __restrict__ x,
        const float* __restrict__ y, const float* __restrict__ lamp,
        float* __restrict__ out) {
    __shared__ float ts[CH * 144];
    __shared__ float red[4 * 64];
    int tid = threadIdx.x;
    int x0 = blockIdx.x * 8, y0 = blockIdx.y * 8;
    for (int i = tid; i < CH * 144; i += 256) {
        int c = i / 144, r = (i / 12) % 12, cL = i % 12;
        int gy = y0 + r - 2, gx = x0 + cL - 2;
        ts[i] = (gy >= 0 && gy < H && gx >= 0 && gx < W)
                ? tin[c * HW + gy * W + gx] : 0.f;
    }
    __syncthreads();
    int g = __builtin_amdgcn_readfirstlane(tid >> 6);
    int px = tid & 63, tx = px & 7, ty = px >> 3;
    float a = 0.f;
    #pragma unroll 1
    for (int cc = 0; cc < 6; ++cc) {
        int c = g * 6 + cc;
        const float* fb = f0t + c * 25;
        #pragma unroll
        for (int u = 0; u < 5; ++u)
            #pragma unroll
            for (int v = 0; v < 5; ++v)
                a = fmaf(ts[c * 144 + (ty + u) * 12 + tx + v], fb[u * 5 + v], a);
    }
    red[g * 64 + px] = a;
    __syncthreads();
    if (g == 0) {
        float t = red[px] + red[64 + px] + red[128 + px] + red[192 + px];
        int pix = (y0 + ty) * W + (x0 + tx);
        float elam = __expf(lamp[0]);
        float xv = x[pix], yv = y[pix];
        out[pix] = xv - (t + elam * (xv - yv));
    }
}

extern "C" void kernel_launch(void* const* d_in, const int* in_sizes, int n_in,
                              void* d_out, int out_size, void* d_ws, size_t ws_size,
                              hipStream_t stream) {
    const float* x    = (const float*)d_in[0];
    const float* y    = (const float*)d_in[1];
    const float* f0   = (const float*)d_in[3];
    const float* f1   = (const float*)d_in[4];
    const float* aw0  = (const float*)d_in[5];
    const float* aw1  = (const float*)d_in[6];
    const float* mean = (const float*)d_in[7];
    const float* lamp = (const float*)d_in[8];
    float* out = (float*)d_out;

    float* w   = (float*)d_ws;
    float* f0n = w;                  // 600
    float* f0t = w + 640;            // 600
    v8s*  abuf = (v8s*)(w + 1536);   // 4864 * 16B = 77824 B
    float* ta  = w + 32768;          // 24*65536
    float* tb  = ta + CH * HW;       // 24*65536

    k_prep<<<19, 256, 0, stream>>>(f0, f1, f0n, f0t, abuf);
    dim3 g8(W / 8, H / 8);           // 32x32
    k_conv1<<<g8, 256, 0, stream>>>(x, f0n, mean, aw0, ta);
    dim3 gm(W / 16, H / 4);          // 16x64 = 1024 blocks
    k_conv24m<0><<<gm, 256, 0, stream>>>(ta, abuf, mean, aw1, tb);
    k_conv24m<1><<<gm, 256, 0, stream>>>(tb, abuf, mean, aw0, ta);
    k_final<<<g8, 256, 0, stream>>>(ta, f0t, x, y, lamp, out);
}

// Round 5
// 67.388 us; speedup vs baseline: 5.9055x; 1.2397x over previous
//
#include <hip/hip_runtime.h>
#include <math.h>

#define H 256
#define W 256
#define HW (H * W)
#define CH 24
#define NK 63

typedef short v8s __attribute__((ext_vector_type(8)));
typedef float v4f __attribute__((ext_vector_type(4)));

// ---------------- RBF helpers: 9-tap window (J=+/-4) -------------------------
__device__ __forceinline__ float rbf_val(float v, const float* ms, const float* ws,
                                         int ch, float m0, float inv_step) {
    int kc = (int)floorf((v - m0) * inv_step + 0.5f);
    kc = min(max(kc, 4), NK - 5);
    float s = 0.f;
    #pragma unroll
    for (int j = 0; j < 9; ++j) {
        int k = kc - 4 + j;
        float d = v - ms[k];
        s = fmaf(__expf(d * d * -0.005f), ws[ch * NK + k], s);
    }
    return s;
}
__device__ __forceinline__ float rbf_der(float v, const float* ms, const float* ws,
                                         int ch, float m0, float inv_step) {
    int kc = (int)floorf((v - m0) * inv_step + 0.5f);
    kc = min(max(kc, 4), NK - 5);
    float s = 0.f;
    #pragma unroll
    for (int j = 0; j < 9; ++j) {
        int k = kc - 4 + j;
        float d = v - ms[k];
        s = fmaf(__expf(d * d * -0.005f) * d * -0.01f, ws[ch * NK + k], s);
    }
    return s;
}

__device__ __forceinline__ short f2bf(float v) {
    unsigned u = __float_as_uint(v);
    u += 0x7fff + ((u >> 16) & 1);
    return (short)(u >> 16);
}

// ---------------- prep: norms, f0n/f0t, MFMA A-fragment pack ------------------
// Abuf: [mode 2][mtile 2][kstep 19][lane 64] v8s. k = tap*24 + c, K 600->608.
__global__ void k_prep(const float* __restrict__ f0, const float* __restrict__ f1,
                       float* __restrict__ f0n, float* __restrict__ f0t,
                       v8s* __restrict__ abuf) {
    __shared__ float red[256];
    int tid = threadIdx.x;
    float s1 = 0.f;
    for (int i = tid; i < 14400; i += 256) s1 += f1[i] * f1[i];
    red[tid] = s1; __syncthreads();
    for (int off = 128; off; off >>= 1) { if (tid < off) red[tid] += red[tid + off]; __syncthreads(); }
    float inv1 = 1.f / sqrtf(red[0]);
    __syncthreads();
    if (blockIdx.x == 0) {
        float s0 = 0.f;
        for (int i = tid; i < 600; i += 256) s0 += f0[i] * f0[i];
        red[tid] = s0; __syncthreads();
        for (int off = 128; off; off >>= 1) { if (tid < off) red[tid] += red[tid + off]; __syncthreads(); }
        float inv0 = 1.f / sqrtf(red[0]);
        for (int i = tid; i < 600; i += 256) {
            int c = i / 25, k = i % 25;
            f0n[i] = f0[i] * inv0;
            f0t[i] = f0[c * 25 + (24 - k)] * inv0;
        }
    }
    int gid = blockIdx.x * 256 + tid;
    int lane = gid & 63;
    int rest = gid >> 6;
    int s = rest % 19;
    int md = rest / 19;
    int mode = md >> 1, m = md & 1;
    int o = m * 16 + (lane & 15);
    v8s av;
    #pragma unroll
    for (int j = 0; j < 8; ++j) {
        int k = 32 * s + 8 * (lane >> 4) + j;
        float wv = 0.f;
        if (o < CH && k < 600) {
            int t = k / 24, c = k % 24;
            wv = (mode == 0) ? f1[(o * CH + c) * 25 + t]
                             : f1[(c * CH + o) * 25 + (24 - t)];
            wv *= inv1;
        }
        av[j] = f2bf(wv);
    }
    abuf[gid] = av;
}

// ---------------- fused A: conv1+rbf0 (haloed, fp32) -> conv2 MFMA + rbf1 ----
// block: 16x8 output tile, 4 waves. t1 LDS region 20x12 (halo 2), ch-minor bf16.
__global__ __launch_bounds__(256) void k_fuseA(const float* __restrict__ x,
        const float* __restrict__ f0n, const v8s* __restrict__ abuf,
        const float* __restrict__ mean, const float* __restrict__ aw0,
        const float* __restrict__ aw1, short* __restrict__ tb) {
    __shared__ __align__(16) short t1[12 * 20 * 24];   // 11520 B
    __shared__ float ms[NK];
    __shared__ float ws0[CH * NK];
    __shared__ float ws1[CH * NK];
    int tid = threadIdx.x;
    int x0 = blockIdx.x * 16, y0 = blockIdx.y * 8;
    for (int i = tid; i < NK; i += 256) ms[i] = mean[i];
    for (int i = tid; i < CH * NK; i += 256) { ws0[i] = aw0[i]; ws1[i] = aw1[i]; }
    __syncthreads();
    float m0 = ms[0];
    float inv_step = (float)(NK - 1) / (ms[NK - 1] - m0);

    // stage 1: t1 = rbf(conv1(pad_rep(x))) on 20x12 haloed region (clamped = rep pad)
    if (tid < 240) {
        int yi = (tid * 3277) >> 16;      // tid / 20
        int xi = tid - yi * 20;
        int sy = min(max(y0 + yi - 2, 0), H - 1);
        int sx = min(max(x0 + xi - 2, 0), W - 1);
        float xv[25];
        #pragma unroll
        for (int u = 0; u < 5; ++u)
            #pragma unroll
            for (int v = 0; v < 5; ++v) {
                int gy = min(max(sy + u - 2, 0), H - 1);
                int gx = min(max(sx + v - 2, 0), W - 1);
                xv[u * 5 + v] = x[gy * W + gx];
            }
        #pragma unroll 1
        for (int og = 0; og < 3; ++og) {
            v8s pk;
            #pragma unroll
            for (int oj = 0; oj < 8; ++oj) {
                int o = og * 8 + oj;
                float a = 0.f;
                #pragma unroll
                for (int k = 0; k < 25; ++k) a = fmaf(xv[k], f0n[o * 25 + k], a);
                pk[oj] = f2bf(rbf_val(a, ms, ws0, o, m0, inv_step));
            }
            *(v8s*)&t1[tid * 24 + og * 8] = pk;
        }
    }
    __syncthreads();

    // stage 2: conv2 via MFMA (mode 0 A-frags), wave w handles rows 2w, 2w+1
    int lane = tid & 63, wv_ = tid >> 6;
    int p = lane & 15, q = lane >> 4;
    v4f a00 = {0.f,0.f,0.f,0.f}, a01 = {0.f,0.f,0.f,0.f};
    v4f a10 = {0.f,0.f,0.f,0.f}, a11 = {0.f,0.f,0.f,0.f};
    int r0 = 2 * wv_, r1 = 2 * wv_ + 1;
    #pragma unroll 1
    for (int s = 0; s < 19; ++s) {
        int k0 = 32 * s + 8 * q;
        int t  = (k0 * 2731) >> 16;
        int c0 = k0 - t * 24;
        int u  = (t * 3277) >> 14;
        int v  = t - 5 * u;
        v8s av0 = abuf[s * 64 + lane];
        v8s av1 = abuf[1216 + s * 64 + lane];
        v8s b0 = *(const v8s*)&t1[((r0 + u) * 20 + (p + v)) * 24 + c0];
        v8s b1 = *(const v8s*)&t1[((r1 + u) * 20 + (p + v)) * 24 + c0];
        a00 = __builtin_amdgcn_mfma_f32_16x16x32_bf16(av0, b0, a00, 0, 0, 0);
        a01 = __builtin_amdgcn_mfma_f32_16x16x32_bf16(av1, b0, a01, 0, 0, 0);
        a10 = __builtin_amdgcn_mfma_f32_16x16x32_bf16(av0, b1, a10, 0, 0, 0);
        a11 = __builtin_amdgcn_mfma_f32_16x16x32_bf16(av1, b1, a11, 0, 0, 0);
    }
    // epilogue: rbf(actw1) -> tb (bf16, channel-major)
    int pix0 = (y0 + r0) * W + (x0 + p);
    int pix1 = (y0 + r1) * W + (x0 + p);
    #pragma unroll
    for (int j = 0; j < 4; ++j) {
        int o = q * 4 + j;
        tb[o * HW + pix0] = f2bf(rbf_val(a00[j], ms, ws1, o, m0, inv_step));
        tb[o * HW + pix1] = f2bf(rbf_val(a10[j], ms, ws1, o, m0, inv_step));
    }
    if (q < 2) {
        #pragma unroll
        for (int j = 0; j < 4; ++j) {
            int o = 16 + q * 4 + j;
            tb[o * HW + pix0] = f2bf(rbf_val(a01[j], ms, ws1, o, m0, inv_step));
            tb[o * HW + pix1] = f2bf(rbf_val(a11[j], ms, ws1, o, m0, inv_step));
        }
    }
}

// ---------------- fused B: convT2 MFMA + rbf' -> convT1 + final --------------
// block: 16x8 output tile. t3 region 20x12 (halo 2, zero outside image),
// computed via flat 16-px N-tiles (16 tiles, last partially masked).
__global__ __launch_bounds__(256) void k_fuseB(const short* __restrict__ tb,
        const v8s* __restrict__ abuf, const float* __restrict__ f0t,
        const float* __restrict__ mean, const float* __restrict__ aw0,
        const float* __restrict__ x, const float* __restrict__ y,
        const float* __restrict__ lamp, float* __restrict__ out) {
    __shared__ __align__(16) short tbt[17 * 24 * 24];  // 19584 B
    __shared__ float t3[240 * 25];                     // 24000 B (stride 25: no conflicts)
    __shared__ float ms[NK];
    __shared__ float ws[CH * NK];
    __shared__ float red[128];
    int tid = threadIdx.x;
    int x0 = blockIdx.x * 16, y0 = blockIdx.y * 8;
    for (int i = tid; i < NK; i += 256) ms[i] = mean[i];
    for (int i = tid; i < CH * NK; i += 256) ws[i] = aw0[i];
    // stage tb tile: rows 0..16 <-> y0-4..y0+12, cols 0..23 <-> x0-4..x0+19, zero pad
    for (int i = tid; i < 17 * 24; i += 256) {
        int ri = (i * 2731) >> 16;        // i / 24
        int ci = i - ri * 24;
        int gy = y0 + ri - 4, gx = x0 + ci - 4;
        short vals[24];
        if (gy >= 0 && gy < H && gx >= 0 && gx < W) {
            const short* src = tb + gy * W + gx;
            #pragma unroll
            for (int c = 0; c < CH; ++c) vals[c] = src[c * HW];
        } else {
            #pragma unroll
            for (int c = 0; c < CH; ++c) vals[c] = 0;
        }
        v8s w0, w1, w2;
        #pragma unroll
        for (int j = 0; j < 8; ++j) { w0[j] = vals[j]; w1[j] = vals[8 + j]; w2[j] = vals[16 + j]; }
        *(v8s*)&tbt[i * 24]      = w0;
        *(v8s*)&tbt[i * 24 + 8]  = w1;
        *(v8s*)&tbt[i * 24 + 16] = w2;
    }
    __syncthreads();
    float m0 = ms[0];
    float inv_step = (float)(NK - 1) / (ms[NK - 1] - m0);

    // convT2 via MFMA (mode 1 A-frags): wave w computes N-tiles 4w..4w+3
    int lane = tid & 63, wv_ = tid >> 6;
    int p = lane & 15, q = lane >> 4;
    const v8s* ap = abuf + 2432;
    int rowg[4], colg[4];
    #pragma unroll
    for (int g = 0; g < 4; ++g) {
        int flat = 16 * (4 * wv_ + g) + p;
        rowg[g] = (flat * 3277) >> 16;    // flat / 20
        colg[g] = flat - rowg[g] * 20;
    }
    v4f acc0[4], acc1[4];
    #pragma unroll
    for (int g = 0; g < 4; ++g) { acc0[g] = (v4f){0.f,0.f,0.f,0.f}; acc1[g] = (v4f){0.f,0.f,0.f,0.f}; }
    #pragma unroll 1
    for (int s = 0; s < 19; ++s) {
        int k0 = 32 * s + 8 * q;
        int t  = (k0 * 2731) >> 16;
        int c0 = k0 - t * 24;
        int u  = (t * 3277) >> 14;
        int v  = t - 5 * u;
        v8s av0 = ap[s * 64 + lane];
        v8s av1 = ap[1216 + s * 64 + lane];
        #pragma unroll
        for (int g = 0; g < 4; ++g) {
            v8s b = *(const v8s*)&tbt[((rowg[g] + u) * 24 + (colg[g] + v)) * 24 + c0];
            acc0[g] = __builtin_amdgcn_mfma_f32_16x16x32_bf16(av0, b, acc0[g], 0, 0, 0);
            acc1[g] = __builtin_amdgcn_mfma_f32_16x16x32_bf16(av1, b, acc1[g], 0, 0, 0);
        }
    }
    // rbf_der -> t3 LDS (zero outside image, mask flat>=240)
    #pragma unroll
    for (int g = 0; g < 4; ++g) {
        int flat = 16 * (4 * wv_ + g) + p;
        if (flat < 240) {
            int gy = y0 + rowg[g] - 2, gx = x0 + colg[g] - 2;
            bool inimg = (gy >= 0 && gy < H && gx >= 0 && gx < W);
            #pragma unroll
            for (int j = 0; j < 4; ++j) {
                int o = q * 4 + j;
                t3[flat * 25 + o] = inimg ? rbf_der(acc0[g][j], ms, ws, o, m0, inv_step) : 0.f;
            }
            if (q < 2) {
                #pragma unroll
                for (int j = 0; j < 4; ++j) {
                    int o = 16 + q * 4 + j;
                    t3[flat * 25 + o] = inimg ? rbf_der(acc1[g][j], ms, ws, o, m0, inv_step) : 0.f;
                }
            }
        }
    }
    __syncthreads();

    // convT1 (24->1, pre-flipped f0t) + final combine; 2-way channel split
    int px = tid & 127, h = tid >> 7;
    int pr = px >> 4, pc = px & 15;
    float a = 0.f;
    #pragma unroll 1
    for (int cc = 0; cc < 12; ++cc) {
        int c = h * 12 + cc;
        const float* fb = f0t + c * 25;
        #pragma unroll
        for (int u = 0; u < 5; ++u)
            #pragma unroll
            for (int v = 0; v < 5; ++v)
                a = fmaf(t3[((pr + u) * 20 + (pc + v)) * 25 + c], fb[u * 5 + v], a);
    }
    if (h == 1) red[px] = a;
    __syncthreads();
    if (h == 0) {
        float tot = a + red[px];
        int pix = (y0 + pr) * W + (x0 + pc);
        float elam = __expf(lamp[0]);
        float xv = x[pix], yv = y[pix];
        out[pix] = xv - (tot + elam * (xv - yv));
    }
}

extern "C" void kernel_launch(void* const* d_in, const int* in_sizes, int n_in,
                              void* d_out, int out_size, void* d_ws, size_t ws_size,
                              hipStream_t stream) {
    const float* x    = (const float*)d_in[0];
    const float* y    = (const float*)d_in[1];
    const float* f0   = (const float*)d_in[3];
    const float* f1   = (const float*)d_in[4];
    const float* aw0  = (const float*)d_in[5];
    const float* aw1  = (const float*)d_in[6];
    const float* mean = (const float*)d_in[7];
    const float* lamp = (const float*)d_in[8];
    float* out = (float*)d_out;

    float* w   = (float*)d_ws;
    float* f0n = w;                  // 600
    float* f0t = w + 640;            // 600
    v8s*  abuf = (v8s*)(w + 1536);   // 4864 * 16 B
    short* tb  = (short*)(w + 32768);

    k_prep<<<19, 256, 0, stream>>>(f0, f1, f0n, f0t, abuf);
    dim3 grid(W / 16, H / 8);        // 16 x 32 = 512 blocks
    k_fuseA<<<grid, 256, 0, stream>>>(x, f0n, abuf, mean, aw0, aw1, tb);
    k_fuseB<<<grid, 256, 0, stream>>>(tb, abuf, f0t, mean, aw0, x, y, lamp, out);
}